// Round 3
// baseline (195.073 us; speedup 1.0000x reference)
//
#include <hip/hip_runtime.h>
#include <hip/hip_bf16.h>
#include <stdint.h>

#define SEQ     2048
#define BATCH   2
#define NHEADS  16
#define HDIM    64
#define DMODEL  1024
#define N3      3072
#define D2      2048
#define MTOT    (BATCH*SEQ)   // 4096

typedef __attribute__((ext_vector_type(4))) float f32x4;
typedef __attribute__((ext_vector_type(8))) short bf16x8;

static __device__ inline unsigned short f2bf(float f) {
    union { float f; unsigned u; } v; v.f = f;
    unsigned r = (v.u + 0x7fffu + ((v.u >> 16) & 1u)) >> 16;
    return (unsigned short)r;
}

// async global->LDS, 16B/lane. LDS dst = wave-uniform base + lane*16 (HW rule).
#define GLDS(gp, lp) __builtin_amdgcn_global_load_lds( \
    (const __attribute__((address_space(1))) void*)(gp), \
    (__attribute__((address_space(3))) void*)(lp), 16, 0, 0)

// ---------------- cast x, w_qkv, w_out to bf16 -------------------------------
__global__ void cast_all(const float* __restrict__ x,
                         const float* __restrict__ wqkv,
                         const float* __restrict__ wout,
                         unsigned short* __restrict__ xb,
                         unsigned short* __restrict__ wqkvb,
                         unsigned short* __restrict__ woutb) {
    long i4 = (long)(blockIdx.x * blockDim.x + threadIdx.x) * 4;
    const float* src; unsigned short* dst; long off;
    if (i4 < 4194304L)      { src = x;    dst = xb;    off = i4; }
    else if (i4 < 7340032L) { src = wqkv; dst = wqkvb; off = i4 - 4194304L; }
    else                    { src = wout; dst = woutb; off = i4 - 7340032L; }
    float4 v = *(const float4*)(src + off);
    ushort4 o;
    o.x = f2bf(v.x); o.y = f2bf(v.y); o.z = f2bf(v.z); o.w = f2bf(v.w);
    *(ushort4*)(dst + off) = o;
}

// ---------------- GEMM qkv: qk out [4096][2048], V out transposed ------------
// C[m,n] = sum_k A[m,k]*B[n,k] + bias[n]; 128x128 tile, BK=32.
// Single-barrier double-buffered GLDS pipeline: prefetch k+1 overlaps compute k.
#define BK 32

__global__ __launch_bounds__(256, 2) void gemm_qkv(
    const unsigned short* __restrict__ A,   // xb [4096][1024]
    const unsigned short* __restrict__ B,   // wqkvb [3072][1024]
    const float* __restrict__ bias,         // [3072]
    unsigned short* __restrict__ qk,        // [4096][2048] bf16 (q|k)
    unsigned short* __restrict__ vT)        // [2048][2048]: [bh*64+d][s]
{
    __shared__ __align__(16) unsigned short sA[2][128][BK];
    __shared__ __align__(16) unsigned short sB[2][128][BK];
    const int tid  = threadIdx.x;
    const int wave = tid >> 6, lane = tid & 63;
    const int quad = lane >> 4, l16 = lane & 15;
    const int wm = wave >> 1, wn = wave & 1;
    const int m0 = blockIdx.x * 128, n0 = blockIdx.y * 128;

    f32x4 acc[4][4];
    const f32x4 zero = {0.f, 0.f, 0.f, 0.f};
    #pragma unroll
    for (int i = 0; i < 4; i++)
        #pragma unroll
        for (int j = 0; j < 4; j++) acc[i][j] = zero;

    const unsigned short* gA0 = A + (long)(m0 + (tid >> 2)) * 1024 + (tid & 3) * 8;
    const unsigned short* gB0 = B + (long)(n0 + (tid >> 2)) * 1024 + (tid & 3) * 8;

    // prologue: stage k0=0 into buf 0
    GLDS(gA0,               &sA[0][wave * 16][0]);
    GLDS(gA0 + 64L * 1024,  &sA[0][64 + wave * 16][0]);
    GLDS(gB0,               &sB[0][wave * 16][0]);
    GLDS(gB0 + 64L * 1024,  &sB[0][64 + wave * 16][0]);

    int buf = 0;
    for (int k0 = 0; k0 < 1024; k0 += BK, buf ^= 1) {
        __syncthreads();   // drains GLDS for buf (vmcnt) + guards buf^1 reuse
        if (k0 + BK < 1024) {
            const unsigned short* ga = gA0 + k0 + BK;
            const unsigned short* gb = gB0 + k0 + BK;
            GLDS(ga,              &sA[buf ^ 1][wave * 16][0]);
            GLDS(ga + 64L * 1024, &sA[buf ^ 1][64 + wave * 16][0]);
            GLDS(gb,              &sB[buf ^ 1][wave * 16][0]);
            GLDS(gb + 64L * 1024, &sB[buf ^ 1][64 + wave * 16][0]);
        }
        bf16x8 af[4], bfr[4];
        #pragma unroll
        for (int mt = 0; mt < 4; mt++)
            af[mt] = *(const bf16x8*)(&sA[buf][wm * 64 + mt * 16 + l16][quad * 8]);
        #pragma unroll
        for (int nt = 0; nt < 4; nt++)
            bfr[nt] = *(const bf16x8*)(&sB[buf][wn * 64 + nt * 16 + l16][quad * 8]);
        #pragma unroll
        for (int mt = 0; mt < 4; mt++)
            #pragma unroll
            for (int nt = 0; nt < 4; nt++)
                acc[mt][nt] = __builtin_amdgcn_mfma_f32_16x16x32_bf16(
                    af[mt], bfr[nt], acc[mt][nt], 0, 0, 0);
    }

    if (n0 < 2048) {   // q|k region: [4096][2048]
        #pragma unroll
        for (int nt = 0; nt < 4; nt++) {
            const int n_g = n0 + wn * 64 + nt * 16 + l16;
            const float bv = bias[n_g];
            #pragma unroll
            for (int mt = 0; mt < 4; mt++) {
                #pragma unroll
                for (int r = 0; r < 4; r++) {
                    const int m_g = m0 + wm * 64 + mt * 16 + quad * 4 + r;
                    qk[(long)m_g * D2 + n_g] = f2bf(acc[mt][nt][r] + bv);
                }
            }
        }
    } else {           // V region: write transposed, packed 8B stores
        const int b = m0 >> 11;
        #pragma unroll
        for (int nt = 0; nt < 4; nt++) {
            const int n_g = n0 + wn * 64 + nt * 16 + l16;
            const int dm = n_g - 2048;
            const long vrow = (long)(((b << 4) + (dm >> 6)) << 6) + (dm & 63);
            const float bv = bias[n_g];
            #pragma unroll
            for (int mt = 0; mt < 4; mt++) {
                const int m_g = m0 + wm * 64 + mt * 16 + quad * 4;
                ushort4 o;
                o.x = f2bf(acc[mt][nt][0] + bv);
                o.y = f2bf(acc[mt][nt][1] + bv);
                o.z = f2bf(acc[mt][nt][2] + bv);
                o.w = f2bf(acc[mt][nt][3] + bv);
                *(ushort4*)(vT + vrow * D2 + (m_g & 2047)) = o;
            }
        }
    }
}

// ---------------- GEMM out: 128x64 tile, same pipeline -----------------------
__global__ __launch_bounds__(256, 2) void gemm_out(
    const unsigned short* __restrict__ A,   // attnb [4096][1024]
    const unsigned short* __restrict__ B,   // woutb [1024][1024]
    const float* __restrict__ bias,         // [1024]
    float* __restrict__ C)                  // d_out fp32 [4096][1024]
{
    __shared__ __align__(16) unsigned short sA[2][128][BK];
    __shared__ __align__(16) unsigned short sB[2][64][BK];
    const int tid  = threadIdx.x;
    const int wave = tid >> 6, lane = tid & 63;
    const int quad = lane >> 4, l16 = lane & 15;
    const int wm = wave >> 1, wn = wave & 1;
    const int m0 = blockIdx.x * 128, n0 = blockIdx.y * 64;

    f32x4 acc[4][2];
    const f32x4 zero = {0.f, 0.f, 0.f, 0.f};
    #pragma unroll
    for (int i = 0; i < 4; i++) { acc[i][0] = zero; acc[i][1] = zero; }

    const unsigned short* gA0 = A + (long)(m0 + (tid >> 2)) * 1024 + (tid & 3) * 8;
    const unsigned short* gB0 = B + (long)(n0 + (tid >> 2)) * 1024 + (tid & 3) * 8;

    GLDS(gA0,              &sA[0][wave * 16][0]);
    GLDS(gA0 + 64L * 1024, &sA[0][64 + wave * 16][0]);
    GLDS(gB0,              &sB[0][wave * 16][0]);   // 64 rows only

    int buf = 0;
    for (int k0 = 0; k0 < 1024; k0 += BK, buf ^= 1) {
        __syncthreads();
        if (k0 + BK < 1024) {
            const unsigned short* ga = gA0 + k0 + BK;
            GLDS(ga,              &sA[buf ^ 1][wave * 16][0]);
            GLDS(ga + 64L * 1024, &sA[buf ^ 1][64 + wave * 16][0]);
            GLDS(gB0 + k0 + BK,   &sB[buf ^ 1][wave * 16][0]);
        }
        bf16x8 af[4], bfr[2];
        #pragma unroll
        for (int mt = 0; mt < 4; mt++)
            af[mt] = *(const bf16x8*)(&sA[buf][wm * 64 + mt * 16 + l16][quad * 8]);
        #pragma unroll
        for (int nt = 0; nt < 2; nt++)
            bfr[nt] = *(const bf16x8*)(&sB[buf][wn * 32 + nt * 16 + l16][quad * 8]);
        #pragma unroll
        for (int mt = 0; mt < 4; mt++)
            #pragma unroll
            for (int nt = 0; nt < 2; nt++)
                acc[mt][nt] = __builtin_amdgcn_mfma_f32_16x16x32_bf16(
                    af[mt], bfr[nt], acc[mt][nt], 0, 0, 0);
    }
    #pragma unroll
    for (int nt = 0; nt < 2; nt++) {
        const int n_g = n0 + wn * 32 + nt * 16 + l16;
        const float bv = bias[n_g];
        #pragma unroll
        for (int mt = 0; mt < 4; mt++) {
            #pragma unroll
            for (int r = 0; r < 4; r++) {
                const int m_g = m0 + wm * 64 + mt * 16 + quad * 4 + r;
                C[(long)m_g * DMODEL + n_g] = acc[mt][nt][r] + bv;
            }
        }
    }
}

// ---------------- flash attention (causal), S^T formulation ------------------
// Block = 4 waves, 128 Q rows (32/wave). KV tiles of 64 staged via swizzled
// GLDS into double buffers; one barrier per tile; prefetch overlaps compute.
// S^T = K·Q^T puts softmax rows on l16 lanes -> in-lane reductions; P written
// [q][kv] (4x ds_write_b64), consumed as B-operand of O^T = V^T·P.
__global__ __launch_bounds__(256, 2) void attn_kernel(
    const unsigned short* __restrict__ qk,   // [4096][2048] bf16 (q|k)
    const unsigned short* __restrict__ vT,   // [2048][2048]: [bh*64+d][s]
    unsigned short* __restrict__ attn)       // [4096][1024] bf16
{
    __shared__ __align__(16) unsigned short sK [2][64][64];  // [kv][d] seg-swizzled
    __shared__ __align__(16) unsigned short sVt[2][64][64];  // [d][kv] seg-swizzled
    __shared__ __align__(16) unsigned short sP [4][2][16][64]; // [wave][qf][q][kv] swizzled

    const int tid  = threadIdx.x;
    const int w    = tid >> 6, lane = tid & 63;
    const int quad = lane >> 4, l16 = lane & 15, l7 = l16 & 7;

    const int bh = blockIdx.x;                     // 0..31
    const int b  = bh >> 4, h = bh & 15;
    const int qtile = 15 - (int)blockIdx.y;        // big tiles dispatched first
    const int qbase = qtile * 128;
    const int ntiles = 2 * qtile + 2;
    const long rowb = (long)b * SEQ;

    // Q fragments (Y-operand rows): q = qbase + w*32 + qf*16 + l16
    bf16x8 qfr[2][2];
    #pragma unroll
    for (int qf = 0; qf < 2; qf++) {
        const int q = qbase + w * 32 + qf * 16 + l16;
        const unsigned short* qp = qk + (rowb + q) * D2 + h * HDIM;
        qfr[qf][0] = *(const bf16x8*)(qp + quad * 8);
        qfr[qf][1] = *(const bf16x8*)(qp + 32 + quad * 8);
    }

    const f32x4 zero = {0.f, 0.f, 0.f, 0.f};
    f32x4 Oacc[4][2];
    #pragma unroll
    for (int mf = 0; mf < 4; mf++) { Oacc[mf][0] = zero; Oacc[mf][1] = zero; }
    float m_i[2] = {-1e30f, -1e30f}, l_i[2] = {0.f, 0.f};

    // staging: lane covers row (w*16 + j*8 + lane>>3), seg swizzled by row&7
    const int rl = lane >> 3;
    const int sm = (lane & 7) ^ (rl & 7);
    const unsigned short* kg  = qk + (rowb + w * 16 + rl) * D2 + 1024 + h * HDIM + sm * 8;
    const unsigned short* kg2 = kg + 8L * D2;
    const unsigned short* vg  = vT + (long)(bh * 64 + w * 16 + rl) * D2 + sm * 8;
    const unsigned short* vg2 = vg + 8L * D2;

    // prologue: stage tile 0 -> buf 0
    GLDS(kg,  &sK [0][w * 16][0]);
    GLDS(kg2, &sK [0][w * 16 + 8][0]);
    GLDS(vg,  &sVt[0][w * 16][0]);
    GLDS(vg2, &sVt[0][w * 16 + 8][0]);

    const int s0 = quad ^ l7;               // swizzled seg for frag reads
    const int wminrow = qbase + w * 32;
    const int wmaxrow = wminrow + 31;
    const float C2 = 0.18033688011112042f;  // 0.125 * log2(e)

    int buf = 0;
    for (int t = 0; t < ntiles; ++t, buf ^= 1) {
        const int kv0 = t * 64;
        __syncthreads();   // tile t staged & visible; prev reads of buf^1 done
        if (t + 1 < ntiles) {   // prefetch t+1 while computing t
            const long offk = (long)(t + 1) * 64 * D2;
            const int  offv = (t + 1) * 64;
            GLDS(kg + offk,  &sK [buf ^ 1][w * 16][0]);
            GLDS(kg2 + offk, &sK [buf ^ 1][w * 16 + 8][0]);
            GLDS(vg + offv,  &sVt[buf ^ 1][w * 16][0]);
            GLDS(vg2 + offv, &sVt[buf ^ 1][w * 16 + 8][0]);
        }
        if (kv0 > wmaxrow) continue;   // fully masked for this wave (still staged)

        // ---- S^T = K·Q^T: lane gets (kv = quad*4+r per kvf, q = l16 per qf) ----
        f32x4 st[4][2];
        #pragma unroll
        for (int kvf = 0; kvf < 4; kvf++) {
            bf16x8 kf0 = *(const bf16x8*)(&sK[buf][kvf * 16 + l16][s0 * 8]);
            bf16x8 kf1 = *(const bf16x8*)(&sK[buf][kvf * 16 + l16][(s0 ^ 4) * 8]);
            #pragma unroll
            for (int qf = 0; qf < 2; qf++) {
                st[kvf][qf] = __builtin_amdgcn_mfma_f32_16x16x32_bf16(kf0, qfr[qf][0], zero, 0, 0, 0);
                st[kvf][qf] = __builtin_amdgcn_mfma_f32_16x16x32_bf16(kf1, qfr[qf][1], st[kvf][qf], 0, 0, 0);
            }
        }
        // ---- causal mask (only tiles crossing the diagonal) ----
        if (kv0 + 63 > wminrow) {
            #pragma unroll
            for (int qf = 0; qf < 2; qf++) {
                const int q = wminrow + qf * 16 + l16;
                #pragma unroll
                for (int kvf = 0; kvf < 4; kvf++) {
                    const int kv = kv0 + kvf * 16 + quad * 4;
                    #pragma unroll
                    for (int r = 0; r < 4; r++)
                        if (kv + r > q) st[kvf][qf][r] = -1e30f;
                }
            }
        }
        // ---- online softmax: rows on l16 lanes, kv in-register ----
        #pragma unroll
        for (int qf = 0; qf < 2; qf++) {
            f32x4 mv0, mv;
            #pragma unroll
            for (int r = 0; r < 4; r++) {
                mv0[r] = fmaxf(st[0][qf][r], st[1][qf][r]);
                mv[r]  = fmaxf(mv0[r], fmaxf(st[2][qf][r], st[3][qf][r]));
            }
            float mx = fmaxf(fmaxf(mv[0], mv[1]), fmaxf(mv[2], mv[3]));
            mx = fmaxf(mx, __shfl_xor(mx, 16));
            mx = fmaxf(mx, __shfl_xor(mx, 32));
            const float mnew  = fmaxf(m_i[qf], mx);
            const float alpha = __builtin_amdgcn_exp2f((m_i[qf] - mnew) * C2);
            const float cm    = mnew * C2;
            #pragma unroll
            for (int kvf = 0; kvf < 4; kvf++) {
                f32x4 a = st[kvf][qf] * C2 - cm;
                #pragma unroll
                for (int r = 0; r < 4; r++)
                    st[kvf][qf][r] = __builtin_amdgcn_exp2f(a[r]);
            }
            f32x4 ps = (st[0][qf] + st[1][qf]) + (st[2][qf] + st[3][qf]);
            l_i[qf] = l_i[qf] * alpha + ((ps[0] + ps[1]) + (ps[2] + ps[3]));
            m_i[qf] = mnew;
            #pragma unroll
            for (int mf = 0; mf < 4; mf++) Oacc[mf][qf] *= alpha;
            // write P[q][kv] (swizzled segs, b64 per kvf)
            #pragma unroll
            for (int kvf = 0; kvf < 4; kvf++) {
                ushort4 o;
                o.x = f2bf(st[kvf][qf][0]); o.y = f2bf(st[kvf][qf][1]);
                o.z = f2bf(st[kvf][qf][2]); o.w = f2bf(st[kvf][qf][3]);
                const int seg = (kvf * 2 + (quad >> 1)) ^ l7;
                *(ushort4*)(&sP[w][qf][l16][seg * 8 + (quad & 1) * 4]) = o;
            }
        }
        // ---- P fragments (B-operand rows = q, contiguous kv) ----
        bf16x8 pf[2][2];
        #pragma unroll
        for (int qf = 0; qf < 2; qf++)
            #pragma unroll
            for (int ks = 0; ks < 2; ks++)
                pf[qf][ks] = *(const bf16x8*)(&sP[w][qf][l16][((ks * 4 + quad) ^ l7) * 8]);
        // ---- O^T += V^T·P: lane gets (d = quad*4+r per mf, q = l16 per qf) ----
        #pragma unroll
        for (int mf = 0; mf < 4; mf++) {
            bf16x8 vf0 = *(const bf16x8*)(&sVt[buf][mf * 16 + l16][s0 * 8]);
            bf16x8 vf1 = *(const bf16x8*)(&sVt[buf][mf * 16 + l16][(s0 ^ 4) * 8]);
            #pragma unroll
            for (int qf = 0; qf < 2; qf++) {
                Oacc[mf][qf] = __builtin_amdgcn_mfma_f32_16x16x32_bf16(vf0, pf[qf][0], Oacc[mf][qf], 0, 0, 0);
                Oacc[mf][qf] = __builtin_amdgcn_mfma_f32_16x16x32_bf16(vf1, pf[qf][1], Oacc[mf][qf], 0, 0, 0);
            }
        }
    }
    // ---- epilogue: attn[q][h*64+d] = O^T[d][q] / l ----
    #pragma unroll
    for (int qf = 0; qf < 2; qf++) {
        float L = l_i[qf];
        L += __shfl_xor(L, 16);
        L += __shfl_xor(L, 32);
        const float inv = 1.0f / L;
        const int q = qbase + w * 32 + qf * 16 + l16;
        unsigned short* op = attn + (rowb + q) * DMODEL + h * HDIM + quad * 4;
        #pragma unroll
        for (int mf = 0; mf < 4; mf++) {
            ushort4 o;
            o.x = f2bf(Oacc[mf][qf][0] * inv);
            o.y = f2bf(Oacc[mf][qf][1] * inv);
            o.z = f2bf(Oacc[mf][qf][2] * inv);
            o.w = f2bf(Oacc[mf][qf][3] * inv);
            *(ushort4*)(op + mf * 16) = o;
        }
    }
}

// -----------------------------------------------------------------------------
extern "C" void kernel_launch(void* const* d_in, const int* in_sizes, int n_in,
                              void* d_out, int out_size, void* d_ws, size_t ws_size,
                              hipStream_t stream) {
    const float* x    = (const float*)d_in[0];
    const float* wqkv = (const float*)d_in[1];
    const float* bqkv = (const float*)d_in[2];
    const float* wout = (const float*)d_in[3];
    const float* bout = (const float*)d_in[4];

    char* ws = (char*)d_ws;
    unsigned short* xb    = (unsigned short*)(ws);                 //  8 MiB
    unsigned short* wqkvb = (unsigned short*)(ws + (8L << 20));    //  6 MiB
    unsigned short* woutb = (unsigned short*)(ws + (14L << 20));   //  2 MiB
    unsigned short* qkb   = (unsigned short*)(ws + (16L << 20));   // 16 MiB
    unsigned short* vTb   = (unsigned short*)(ws + (32L << 20));   //  8 MiB
    unsigned short* attnb = (unsigned short*)(ws + (40L << 20));   //  8 MiB

    cast_all<<<8192, 256, 0, stream>>>(x, wqkv, wout, xb, wqkvb, woutb);

    dim3 g1(32, 24);   // M/128, N3/128 (y<16: q|k, y>=16: vT)
    gemm_qkv<<<g1, 256, 0, stream>>>(xb, wqkvb, bqkv, qkb, vTb);

    dim3 g2(32, 16);   // bh, qtiles of 128 (reversed: big first)
    attn_kernel<<<g2, 256, 0, stream>>>(qkb, vTb, attnb);

    dim3 g3(32, 16);   // M/128, DMODEL/64
    gemm_out<<<g3, 256, 0, stream>>>(attnb, woutb, bout, (float*)d_out);
}

// Round 4
// 186.098 us; speedup vs baseline: 1.0482x; 1.0482x over previous
//
#include <hip/hip_runtime.h>
#include <hip/hip_bf16.h>
#include <stdint.h>

#define SEQ     2048
#define BATCH   2
#define NHEADS  16
#define HDIM    64
#define DMODEL  1024
#define N3      3072
#define D2      2048
#define MTOT    (BATCH*SEQ)   // 4096

typedef __attribute__((ext_vector_type(4))) float f32x4;
typedef __attribute__((ext_vector_type(8))) short bf16x8;

static __device__ inline unsigned short f2bf(float f) {
    union { float f; unsigned u; } v; v.f = f;
    unsigned r = (v.u + 0x7fffu + ((v.u >> 16) & 1u)) >> 16;
    return (unsigned short)r;
}

// async global->LDS, 16B/lane. LDS dst = wave-uniform base + lane*16 (HW rule).
#define GLDS(gp, lp) __builtin_amdgcn_global_load_lds( \
    (const __attribute__((address_space(1))) void*)(gp), \
    (__attribute__((address_space(3))) void*)(lp), 16, 0, 0)

// ---------------- cast x, w_qkv, w_out to bf16 -------------------------------
__global__ void cast_all(const float* __restrict__ x,
                         const float* __restrict__ wqkv,
                         const float* __restrict__ wout,
                         unsigned short* __restrict__ xb,
                         unsigned short* __restrict__ wqkvb,
                         unsigned short* __restrict__ woutb) {
    long i4 = (long)(blockIdx.x * blockDim.x + threadIdx.x) * 4;
    const float* src; unsigned short* dst; long off;
    if (i4 < 4194304L)      { src = x;    dst = xb;    off = i4; }
    else if (i4 < 7340032L) { src = wqkv; dst = wqkvb; off = i4 - 4194304L; }
    else                    { src = wout; dst = woutb; off = i4 - 7340032L; }
    float4 v = *(const float4*)(src + off);
    ushort4 o;
    o.x = f2bf(v.x); o.y = f2bf(v.y); o.z = f2bf(v.z); o.w = f2bf(v.w);
    *(ushort4*)(dst + off) = o;
}

// ---------------- GEMM qkv: qk out [4096][2048], V out transposed ------------
#define BK 32

__global__ __launch_bounds__(256, 2) void gemm_qkv(
    const unsigned short* __restrict__ A,   // xb [4096][1024]
    const unsigned short* __restrict__ B,   // wqkvb [3072][1024]
    const float* __restrict__ bias,         // [3072]
    unsigned short* __restrict__ qk,        // [4096][2048] bf16 (q|k)
    unsigned short* __restrict__ vT)        // [2048][2048]: [bh*64+d][s]
{
    __shared__ __align__(16) unsigned short sA[2][128][BK];
    __shared__ __align__(16) unsigned short sB[2][128][BK];
    const int tid  = threadIdx.x;
    const int wave = tid >> 6, lane = tid & 63;
    const int quad = lane >> 4, l16 = lane & 15;
    const int wm = wave >> 1, wn = wave & 1;
    const int m0 = blockIdx.x * 128, n0 = blockIdx.y * 128;

    f32x4 acc[4][4];
    const f32x4 zero = {0.f, 0.f, 0.f, 0.f};
    #pragma unroll
    for (int i = 0; i < 4; i++)
        #pragma unroll
        for (int j = 0; j < 4; j++) acc[i][j] = zero;

    const unsigned short* gA0 = A + (long)(m0 + (tid >> 2)) * 1024 + (tid & 3) * 8;
    const unsigned short* gB0 = B + (long)(n0 + (tid >> 2)) * 1024 + (tid & 3) * 8;

    GLDS(gA0,               &sA[0][wave * 16][0]);
    GLDS(gA0 + 64L * 1024,  &sA[0][64 + wave * 16][0]);
    GLDS(gB0,               &sB[0][wave * 16][0]);
    GLDS(gB0 + 64L * 1024,  &sB[0][64 + wave * 16][0]);

    int buf = 0;
    for (int k0 = 0; k0 < 1024; k0 += BK, buf ^= 1) {
        __syncthreads();
        if (k0 + BK < 1024) {
            const unsigned short* ga = gA0 + k0 + BK;
            const unsigned short* gb = gB0 + k0 + BK;
            GLDS(ga,              &sA[buf ^ 1][wave * 16][0]);
            GLDS(ga + 64L * 1024, &sA[buf ^ 1][64 + wave * 16][0]);
            GLDS(gb,              &sB[buf ^ 1][wave * 16][0]);
            GLDS(gb + 64L * 1024, &sB[buf ^ 1][64 + wave * 16][0]);
        }
        bf16x8 af[4], bfr[4];
        #pragma unroll
        for (int mt = 0; mt < 4; mt++)
            af[mt] = *(const bf16x8*)(&sA[buf][wm * 64 + mt * 16 + l16][quad * 8]);
        #pragma unroll
        for (int nt = 0; nt < 4; nt++)
            bfr[nt] = *(const bf16x8*)(&sB[buf][wn * 64 + nt * 16 + l16][quad * 8]);
        #pragma unroll
        for (int mt = 0; mt < 4; mt++)
            #pragma unroll
            for (int nt = 0; nt < 4; nt++)
                acc[mt][nt] = __builtin_amdgcn_mfma_f32_16x16x32_bf16(
                    af[mt], bfr[nt], acc[mt][nt], 0, 0, 0);
    }

    if (n0 < 2048) {   // q|k region: [4096][2048]
        #pragma unroll
        for (int nt = 0; nt < 4; nt++) {
            const int n_g = n0 + wn * 64 + nt * 16 + l16;
            const float bv = bias[n_g];
            #pragma unroll
            for (int mt = 0; mt < 4; mt++) {
                #pragma unroll
                for (int r = 0; r < 4; r++) {
                    const int m_g = m0 + wm * 64 + mt * 16 + quad * 4 + r;
                    qk[(long)m_g * D2 + n_g] = f2bf(acc[mt][nt][r] + bv);
                }
            }
        }
    } else {           // V region: write transposed, packed 8B stores
        const int b = m0 >> 11;
        #pragma unroll
        for (int nt = 0; nt < 4; nt++) {
            const int n_g = n0 + wn * 64 + nt * 16 + l16;
            const int dm = n_g - 2048;
            const long vrow = (long)(((b << 4) + (dm >> 6)) << 6) + (dm & 63);
            const float bv = bias[n_g];
            #pragma unroll
            for (int mt = 0; mt < 4; mt++) {
                const int m_g = m0 + wm * 64 + mt * 16 + quad * 4;
                ushort4 o;
                o.x = f2bf(acc[mt][nt][0] + bv);
                o.y = f2bf(acc[mt][nt][1] + bv);
                o.z = f2bf(acc[mt][nt][2] + bv);
                o.w = f2bf(acc[mt][nt][3] + bv);
                *(ushort4*)(vT + vrow * D2 + (m_g & 2047)) = o;
            }
        }
    }
}

// ---------------- GEMM out: 128x64 tile --------------------------------------
__global__ __launch_bounds__(256, 2) void gemm_out(
    const unsigned short* __restrict__ A,   // attnb [4096][1024]
    const unsigned short* __restrict__ B,   // woutb [1024][1024]
    const float* __restrict__ bias,         // [1024]
    float* __restrict__ C)                  // d_out fp32 [4096][1024]
{
    __shared__ __align__(16) unsigned short sA[2][128][BK];
    __shared__ __align__(16) unsigned short sB[2][64][BK];
    const int tid  = threadIdx.x;
    const int wave = tid >> 6, lane = tid & 63;
    const int quad = lane >> 4, l16 = lane & 15;
    const int wm = wave >> 1, wn = wave & 1;
    const int m0 = blockIdx.x * 128, n0 = blockIdx.y * 64;

    f32x4 acc[4][2];
    const f32x4 zero = {0.f, 0.f, 0.f, 0.f};
    #pragma unroll
    for (int i = 0; i < 4; i++) { acc[i][0] = zero; acc[i][1] = zero; }

    const unsigned short* gA0 = A + (long)(m0 + (tid >> 2)) * 1024 + (tid & 3) * 8;
    const unsigned short* gB0 = B + (long)(n0 + (tid >> 2)) * 1024 + (tid & 3) * 8;

    GLDS(gA0,              &sA[0][wave * 16][0]);
    GLDS(gA0 + 64L * 1024, &sA[0][64 + wave * 16][0]);
    GLDS(gB0,              &sB[0][wave * 16][0]);

    int buf = 0;
    for (int k0 = 0; k0 < 1024; k0 += BK, buf ^= 1) {
        __syncthreads();
        if (k0 + BK < 1024) {
            const unsigned short* ga = gA0 + k0 + BK;
            GLDS(ga,              &sA[buf ^ 1][wave * 16][0]);
            GLDS(ga + 64L * 1024, &sA[buf ^ 1][64 + wave * 16][0]);
            GLDS(gB0 + k0 + BK,   &sB[buf ^ 1][wave * 16][0]);
        }
        bf16x8 af[4], bfr[2];
        #pragma unroll
        for (int mt = 0; mt < 4; mt++)
            af[mt] = *(const bf16x8*)(&sA[buf][wm * 64 + mt * 16 + l16][quad * 8]);
        #pragma unroll
        for (int nt = 0; nt < 2; nt++)
            bfr[nt] = *(const bf16x8*)(&sB[buf][wn * 32 + nt * 16 + l16][quad * 8]);
        #pragma unroll
        for (int mt = 0; mt < 4; mt++)
            #pragma unroll
            for (int nt = 0; nt < 2; nt++)
                acc[mt][nt] = __builtin_amdgcn_mfma_f32_16x16x32_bf16(
                    af[mt], bfr[nt], acc[mt][nt], 0, 0, 0);
    }
    #pragma unroll
    for (int nt = 0; nt < 2; nt++) {
        const int n_g = n0 + wn * 32 + nt * 16 + l16;
        const float bv = bias[n_g];
        #pragma unroll
        for (int mt = 0; mt < 4; mt++) {
            #pragma unroll
            for (int r = 0; r < 4; r++) {
                const int m_g = m0 + wm * 64 + mt * 16 + quad * 4 + r;
                C[(long)m_g * DMODEL + n_g] = acc[mt][nt][r] + bv;
            }
        }
    }
}

// ---------------- flash attention (causal), S^T, qtile-paired ----------------
// Block (bh, p) handles qtile p then qtile 31-p: (p+1)+(32-p)=33 KV tiles for
// EVERY block -> 512 uniform blocks, no tail. 64 q rows/phase, 16/wave.
// KV staged 2 tiles per barrier window (2 bufs x 2 subs) via swizzled GLDS.
__global__ __launch_bounds__(256, 2) void attn_kernel(
    const unsigned short* __restrict__ qk,   // [4096][2048] bf16 (q|k)
    const unsigned short* __restrict__ vT,   // [2048][2048]: [bh*64+d][s]
    unsigned short* __restrict__ attn)       // [4096][1024] bf16
{
    __shared__ __align__(16) unsigned short sK [2][2][64][64];  // [buf][sub][kv][d]
    __shared__ __align__(16) unsigned short sVt[2][2][64][64];  // [buf][sub][d][kv]
    __shared__ __align__(16) unsigned short sP [4][16][64];     // [wave][q][kv]

    const int tid  = threadIdx.x;
    const int w    = tid >> 6, lane = tid & 63;
    const int quad = lane >> 4, l16 = lane & 15, l7 = l16 & 7;

    const int bh = blockIdx.x;                     // 0..31
    const int b  = bh >> 4, h = bh & 15;
    const int pair = blockIdx.y;                   // 0..15
    const long rowb = (long)b * SEQ;

    // staging: lane covers row (w*16 + i*8 + rl), seg swizzled by row&7
    const int rl = lane >> 3;                      // 0..7
    const int sm = (lane & 7) ^ rl;
    const unsigned short* kg = qk + (rowb + w * 16 + rl) * D2 + 1024 + h * HDIM + sm * 8;
    const unsigned short* vg = vT + (long)(bh * 64 + w * 16 + rl) * D2 + sm * 8;

    const int s0 = quad ^ l7;                      // swizzled seg for frag reads
    const float C2 = 0.18033688011112042f;         // 0.125 * log2(e)
    const f32x4 zero = {0.f, 0.f, 0.f, 0.f};

    #pragma unroll
    for (int ph = 0; ph < 2; ph++) {
        const int qtile  = ph ? (31 - pair) : pair;
        const int qbase  = qtile * 64;
        const int ntiles = qtile + 1;
        const int npairs = (ntiles + 1) >> 1;

        // Q fragments (B-operand rows = q = qbase + w*16 + l16)
        bf16x8 qf0, qf1;
        {
            const unsigned short* qp = qk + (rowb + qbase + w * 16 + l16) * D2 + h * HDIM;
            qf0 = *(const bf16x8*)(qp + quad * 8);
            qf1 = *(const bf16x8*)(qp + 32 + quad * 8);
        }
        f32x4 Oacc[4];
        #pragma unroll
        for (int mf = 0; mf < 4; mf++) Oacc[mf] = zero;
        float m_i = -1e30f, l_i = 0.f;

        __syncthreads();   // all waves done reading LDS from previous phase
        // prologue: stage pair 0 (tiles 0, min(1,qtile)) into buf 0
        {
            const long o0 = 0, o1 = (long)(1 <= qtile ? 1 : qtile) * 64;
            GLDS(kg + o0 * D2,           &sK [0][0][w * 16][0]);
            GLDS(kg + o0 * D2 + 8L * D2, &sK [0][0][w * 16 + 8][0]);
            GLDS(vg + o0,                &sVt[0][0][w * 16][0]);
            GLDS(vg + o0 + 8L * D2,      &sVt[0][0][w * 16 + 8][0]);
            GLDS(kg + o1 * D2,           &sK [0][1][w * 16][0]);
            GLDS(kg + o1 * D2 + 8L * D2, &sK [0][1][w * 16 + 8][0]);
            GLDS(vg + o1,                &sVt[0][1][w * 16][0]);
            GLDS(vg + o1 + 8L * D2,      &sVt[0][1][w * 16 + 8][0]);
        }

        int buf = 0;
        for (int p = 0; p < npairs; p++, buf ^= 1) {
            __syncthreads();   // pair p staged & visible; reads of buf^1 done
            if (p + 1 < npairs) {
                const int t0 = 2 * p + 2, t1 = 2 * p + 3;
                const long o0 = (long)(t0 <= qtile ? t0 : qtile) * 64;
                const long o1 = (long)(t1 <= qtile ? t1 : qtile) * 64;
                GLDS(kg + o0 * D2,           &sK [buf ^ 1][0][w * 16][0]);
                GLDS(kg + o0 * D2 + 8L * D2, &sK [buf ^ 1][0][w * 16 + 8][0]);
                GLDS(vg + o0,                &sVt[buf ^ 1][0][w * 16][0]);
                GLDS(vg + o0 + 8L * D2,      &sVt[buf ^ 1][0][w * 16 + 8][0]);
                GLDS(kg + o1 * D2,           &sK [buf ^ 1][1][w * 16][0]);
                GLDS(kg + o1 * D2 + 8L * D2, &sK [buf ^ 1][1][w * 16 + 8][0]);
                GLDS(vg + o1,                &sVt[buf ^ 1][1][w * 16][0]);
                GLDS(vg + o1 + 8L * D2,      &sVt[buf ^ 1][1][w * 16 + 8][0]);
            }
            #pragma unroll
            for (int s = 0; s < 2; s++) {
                const int t = 2 * p + s;
                if (t >= ntiles) break;

                // ---- S^T = K·Q^T: lane gets (kv = kvf*16+quad*4+r, q = l16) ----
                f32x4 st[4];
                #pragma unroll
                for (int kvf = 0; kvf < 4; kvf++) {
                    bf16x8 kf0 = *(const bf16x8*)(&sK[buf][s][kvf * 16 + l16][s0 * 8]);
                    bf16x8 kf1 = *(const bf16x8*)(&sK[buf][s][kvf * 16 + l16][(s0 ^ 4) * 8]);
                    st[kvf] = __builtin_amdgcn_mfma_f32_16x16x32_bf16(kf0, qf0, zero, 0, 0, 0);
                    st[kvf] = __builtin_amdgcn_mfma_f32_16x16x32_bf16(kf1, qf1, st[kvf], 0, 0, 0);
                }
                // ---- causal mask: only the diagonal tile ----
                if (t == qtile) {
                    const int ql = w * 16 + l16;     // local q (qbase cancels)
                    #pragma unroll
                    for (int kvf = 0; kvf < 4; kvf++) {
                        const int kv = kvf * 16 + quad * 4;
                        #pragma unroll
                        for (int r = 0; r < 4; r++)
                            if (kv + r > ql) st[kvf][r] = -1e30f;
                    }
                }
                // ---- online softmax: row q on l16 lanes, kv in-register ----
                f32x4 mv;
                #pragma unroll
                for (int r = 0; r < 4; r++)
                    mv[r] = fmaxf(fmaxf(st[0][r], st[1][r]), fmaxf(st[2][r], st[3][r]));
                float mx = fmaxf(fmaxf(mv[0], mv[1]), fmaxf(mv[2], mv[3]));
                mx = fmaxf(mx, __shfl_xor(mx, 16));
                mx = fmaxf(mx, __shfl_xor(mx, 32));
                const float mnew  = fmaxf(m_i, mx);
                const float alpha = __builtin_amdgcn_exp2f((m_i - mnew) * C2);
                const float cm    = mnew * C2;
                #pragma unroll
                for (int kvf = 0; kvf < 4; kvf++) {
                    f32x4 a = st[kvf] * C2 - cm;
                    #pragma unroll
                    for (int r = 0; r < 4; r++)
                        st[kvf][r] = __builtin_amdgcn_exp2f(a[r]);
                }
                f32x4 ps = (st[0] + st[1]) + (st[2] + st[3]);
                l_i = l_i * alpha + ((ps[0] + ps[1]) + (ps[2] + ps[3]));
                m_i = mnew;
                #pragma unroll
                for (int mf = 0; mf < 4; mf++) Oacc[mf] *= alpha;

                // ---- P: C-layout -> B-operand layout via per-wave LDS ----
                #pragma unroll
                for (int kvf = 0; kvf < 4; kvf++) {
                    ushort4 o;
                    o.x = f2bf(st[kvf][0]); o.y = f2bf(st[kvf][1]);
                    o.z = f2bf(st[kvf][2]); o.w = f2bf(st[kvf][3]);
                    const int seg = (kvf * 2 + (quad >> 1)) ^ l7;
                    *(ushort4*)(&sP[w][l16][seg * 8 + (quad & 1) * 4]) = o;
                }
                bf16x8 pf0 = *(const bf16x8*)(&sP[w][l16][((quad) ^ l7) * 8]);
                bf16x8 pf1 = *(const bf16x8*)(&sP[w][l16][((4 + quad) ^ l7) * 8]);
                // ---- O^T += V^T·P: lane gets (d = mf*16+quad*4+r, q = l16) ----
                #pragma unroll
                for (int mf = 0; mf < 4; mf++) {
                    bf16x8 vf0 = *(const bf16x8*)(&sVt[buf][s][mf * 16 + l16][s0 * 8]);
                    bf16x8 vf1 = *(const bf16x8*)(&sVt[buf][s][mf * 16 + l16][(s0 ^ 4) * 8]);
                    Oacc[mf] = __builtin_amdgcn_mfma_f32_16x16x32_bf16(vf0, pf0, Oacc[mf], 0, 0, 0);
                    Oacc[mf] = __builtin_amdgcn_mfma_f32_16x16x32_bf16(vf1, pf1, Oacc[mf], 0, 0, 0);
                }
            }
        }
        // ---- epilogue: attn[q][h*64+d] = O^T[d][q] / l ----
        float L = l_i;
        L += __shfl_xor(L, 16);
        L += __shfl_xor(L, 32);
        const float inv = 1.0f / L;
        const int q = qbase + w * 16 + l16;
        unsigned short* op = attn + (rowb + q) * DMODEL + h * HDIM + quad * 4;
        #pragma unroll
        for (int mf = 0; mf < 4; mf++) {
            ushort4 o;
            o.x = f2bf(Oacc[mf][0] * inv);
            o.y = f2bf(Oacc[mf][1] * inv);
            o.z = f2bf(Oacc[mf][2] * inv);
            o.w = f2bf(Oacc[mf][3] * inv);
            *(ushort4*)(op + mf * 16) = o;
        }
    }
}

// -----------------------------------------------------------------------------
extern "C" void kernel_launch(void* const* d_in, const int* in_sizes, int n_in,
                              void* d_out, int out_size, void* d_ws, size_t ws_size,
                              hipStream_t stream) {
    const float* x    = (const float*)d_in[0];
    const float* wqkv = (const float*)d_in[1];
    const float* bqkv = (const float*)d_in[2];
    const float* wout = (const float*)d_in[3];
    const float* bout = (const float*)d_in[4];

    char* ws = (char*)d_ws;
    unsigned short* xb    = (unsigned short*)(ws);                 //  8 MiB
    unsigned short* wqkvb = (unsigned short*)(ws + (8L << 20));    //  6 MiB
    unsigned short* woutb = (unsigned short*)(ws + (14L << 20));   //  2 MiB
    unsigned short* qkb   = (unsigned short*)(ws + (16L << 20));   // 16 MiB
    unsigned short* vTb   = (unsigned short*)(ws + (32L << 20));   //  8 MiB
    unsigned short* attnb = (unsigned short*)(ws + (40L << 20));   //  8 MiB

    cast_all<<<8192, 256, 0, stream>>>(x, wqkv, wout, xb, wqkvb, woutb);

    dim3 g1(32, 24);   // M/128, N3/128 (y<16: q|k, y>=16: vT)
    gemm_qkv<<<g1, 256, 0, stream>>>(xb, wqkvb, bqkv, qkb, vTb);

    dim3 g2(32, 16);   // bh, qtile-pairs (uniform 33 tiles/block)
    attn_kernel<<<g2, 256, 0, stream>>>(qkb, vTb, attnb);

    dim3 g3(32, 16);   // M/128, DMODEL/64
    gemm_out<<<g3, 256, 0, stream>>>(attnb, woutb, bout, (float*)d_out);
}